// Round 1
// baseline (866.562 us; speedup 1.0000x reference)
//
#include <hip/hip_runtime.h>

constexpr int Kk = 27;
constexpr int Mm = 131072;
constexpr int Nn = 524288;
constexpr int Cc = 64;
constexpr float BN_EPS = 1e-5f;

constexpr int ROWS_PER_WAVE = 32;
constexpr int WAVES_PER_BLOCK = 4;
constexpr int ROWS_PER_BLOCK = ROWS_PER_WAVE * WAVES_PER_BLOCK;  // 128
constexpr int BLOCKS_PER_K = Mm / ROWS_PER_BLOCK;                // 1024

// One wave per gathered row. Lane c computes output channel c.
// W[k] column c lives in 64 VGPRs; x rows staged via LDS (coalesced gather,
// broadcast ds_read_b128 on compute). Scatter via device-scope f32 atomics.
__global__ __launch_bounds__(256) void scatter_gemm_kernel(
    const float* __restrict__ x, const float* __restrict__ W,
    const int* __restrict__ in_idx, const int* __restrict__ out_idx,
    float* __restrict__ out)
{
    const int tid  = threadIdx.x;
    const int lane = tid & 63;
    const int w    = tid >> 6;
    const int k     = blockIdx.x / BLOCKS_PER_K;
    const int chunk = blockIdx.x % BLOCKS_PER_K;
    const int m0    = chunk * ROWS_PER_BLOCK + w * ROWS_PER_WAVE;

    // Per-lane column of W[k]: wcol[i] = W[k][i][lane]
    const float* Wk = W + k * (Cc * Cc);
    float wcol[Cc];
#pragma unroll
    for (int i = 0; i < Cc; ++i) wcol[i] = Wk[i * Cc + lane];

    const int* inI  = in_idx  + (size_t)k * Mm + m0;
    const int* outI = out_idx + (size_t)k * Mm + m0;

    __shared__ float xs[WAVES_PER_BLOCK][ROWS_PER_WAVE][Cc];  // 32 KB

    // Stage all 32 rows (coalesced 256B gathers, 32 loads in flight)
    for (int r = 0; r < ROWS_PER_WAVE; ++r) {
        const int irow = inI[r];
        xs[w][r][lane] = x[(size_t)irow * Cc + lane];
    }

    // Compute + scatter
    for (int r = 0; r < ROWS_PER_WAVE; ++r) {
        const float* xr = &xs[w][r][0];
        float acc = 0.f;
#pragma unroll
        for (int i = 0; i < Cc; i += 4) {
            const float4 xv = *reinterpret_cast<const float4*>(xr + i);  // broadcast
            acc = fmaf(xv.x, wcol[i + 0], acc);
            acc = fmaf(xv.y, wcol[i + 1], acc);
            acc = fmaf(xv.z, wcol[i + 2], acc);
            acc = fmaf(xv.w, wcol[i + 3], acc);
        }
        const int orow = outI[r];
        atomicAdd(out + (size_t)orow * Cc + lane, acc);
    }
}

constexpr int STAT_BLOCKS = 1024;

__global__ __launch_bounds__(256) void bn_stats_kernel(
    const float* __restrict__ out, float* __restrict__ stats)
{
    const int tid = threadIdx.x;
    const int c = tid & 63;
    const int g = tid >> 6;
    float s = 0.f, sq = 0.f;
    for (int r = blockIdx.x * 4 + g; r < Nn; r += gridDim.x * 4) {
        const float v = out[(size_t)r * Cc + c];
        s += v;
        sq = fmaf(v, v, sq);
    }
    __shared__ float lsum[4][64];
    __shared__ float lsq[4][64];
    lsum[g][c] = s;
    lsq[g][c]  = sq;
    __syncthreads();
    if (tid < 64) {
        const float ts = lsum[0][c] + lsum[1][c] + lsum[2][c] + lsum[3][c];
        const float tq = lsq[0][c] + lsq[1][c] + lsq[2][c] + lsq[3][c];
        atomicAdd(stats + c, ts);
        atomicAdd(stats + 64 + c, tq);
    }
}

__global__ void bn_finalize_kernel(const float* __restrict__ stats,
                                   const float* __restrict__ gamma,
                                   const float* __restrict__ beta,
                                   float* __restrict__ ss)
{
    const int c = threadIdx.x;  // 64 threads
    const float inv_n = 1.f / (float)Nn;
    const float mean = stats[c] * inv_n;
    const float var  = stats[64 + c] * inv_n - mean * mean;
    const float scale = gamma[c] * rsqrtf(var + BN_EPS);
    ss[c]      = scale;
    ss[64 + c] = beta[c] - mean * scale;
}

__global__ __launch_bounds__(256) void bn_apply_kernel(
    float* __restrict__ out, const float* __restrict__ ss)
{
    const size_t total4 = (size_t)Nn * Cc / 4;
    const float4* ssc = reinterpret_cast<const float4*>(ss);
    float4* o4 = reinterpret_cast<float4*>(out);
    for (size_t i = (size_t)blockIdx.x * blockDim.x + threadIdx.x; i < total4;
         i += (size_t)gridDim.x * blockDim.x) {
        const int c4 = (int)(i & 15);          // 16 float4 per row
        const float4 sc = ssc[c4];
        const float4 sh = ssc[16 + c4];
        float4 v = o4[i];
        v.x = fmaxf(fmaf(v.x, sc.x, sh.x), 0.f);
        v.y = fmaxf(fmaf(v.y, sc.y, sh.y), 0.f);
        v.z = fmaxf(fmaf(v.z, sc.z, sh.z), 0.f);
        v.w = fmaxf(fmaf(v.w, sc.w, sh.w), 0.f);
        o4[i] = v;
    }
}

extern "C" void kernel_launch(void* const* d_in, const int* in_sizes, int n_in,
                              void* d_out, int out_size, void* d_ws, size_t ws_size,
                              hipStream_t stream) {
    const float* x      = (const float*)d_in[0];
    const float* W      = (const float*)d_in[1];
    const float* gamma  = (const float*)d_in[2];
    const float* beta   = (const float*)d_in[3];
    const int*   in_idx = (const int*)d_in[4];
    const int*   out_idx= (const int*)d_in[5];
    float* out   = (float*)d_out;
    float* stats = (float*)d_ws;        // 128 floats: sum | sumsq
    float* ss    = stats + 128;         // 128 floats: scale | shift

    hipMemsetAsync(d_out, 0, (size_t)Nn * Cc * sizeof(float), stream);
    hipMemsetAsync(d_ws, 0, 256 * sizeof(float), stream);

    scatter_gemm_kernel<<<Kk * BLOCKS_PER_K, 256, 0, stream>>>(x, W, in_idx, out_idx, out);
    bn_stats_kernel<<<STAT_BLOCKS, 256, 0, stream>>>(out, stats);
    bn_finalize_kernel<<<1, 64, 0, stream>>>(stats, gamma, beta, ss);
    bn_apply_kernel<<<4096, 256, 0, stream>>>(out, ss);
}

// Round 2
// 865.409 us; speedup vs baseline: 1.0013x; 1.0013x over previous
//
#include <hip/hip_runtime.h>
#include <hip/hip_bf16.h>

constexpr int Kk = 27;
constexpr int Mm = 131072;
constexpr int Nn = 524288;
constexpr int Cc = 64;
constexpr float BN_EPS = 1e-5f;

typedef __attribute__((ext_vector_type(8))) short bf16x8;
typedef __attribute__((ext_vector_type(4))) float f32x4;

// ---------------- ws layout ----------------
// [0,512)      : stats (128 f32: sum | sumsq)
// [512,1024)   : ss (128 f32: scale | shift)
// [1024, +221184) : W bf16 fragments (27 * 4096 ushort)
// [222208, +67108864) : x bf16 (N*64 ushort)
constexpr size_t WF_OFF = 1024;
constexpr size_t WF_BYTES = (size_t)Kk * 4096 * 2;
constexpr size_t XB_OFF = WF_OFF + WF_BYTES;           // 222208, 16B aligned
constexpr size_t XB_BYTES = (size_t)Nn * Cc * 2;
constexpr size_t WS_NEEDED = XB_OFF + XB_BYTES;

static __device__ __forceinline__ unsigned short f2bf(float f) {
    __hip_bfloat16 h = __float2bfloat16(f);
    return *reinterpret_cast<unsigned short*>(&h);
}

// ---------------- converts ----------------
__global__ __launch_bounds__(256) void convert_x_kernel(
    const float* __restrict__ x, unsigned short* __restrict__ xb)
{
    const size_t total4 = (size_t)Nn * Cc / 4;
    for (size_t i = (size_t)blockIdx.x * blockDim.x + threadIdx.x; i < total4;
         i += (size_t)gridDim.x * blockDim.x) {
        const float4 v = reinterpret_cast<const float4*>(x)[i];
        ushort4 o;
        o.x = f2bf(v.x); o.y = f2bf(v.y); o.z = f2bf(v.z); o.w = f2bf(v.w);
        reinterpret_cast<ushort4*>(xb)[i] = o;
    }
}

// Wf[((k*8 + ct*2 + kk)*64 + lane)*8 + j] = bf16( W[k][kk*32+(lane>>4)*8+j][ct*16+(lane&15)] )
__global__ __launch_bounds__(256) void convert_w_kernel(
    const float* __restrict__ W, unsigned short* __restrict__ Wf)
{
    const int t = blockIdx.x * blockDim.x + threadIdx.x;  // 27*4096 total
    if (t >= Kk * 4096) return;
    const int j    = t & 7;
    const int lane = (t >> 3) & 63;
    const int kk   = (t >> 9) & 1;
    const int ct   = (t >> 10) & 3;
    const int k    = t >> 12;
    const int cin  = kk * 32 + ((lane >> 4) & 3) * 8 + j;
    const int cout = ct * 16 + (lane & 15);
    Wf[t] = f2bf(W[(size_t)k * 4096 + cin * 64 + cout]);
}

// ---------------- MFMA gather-GEMM-scatter ----------------
constexpr int RPB2 = 256;            // rows per block (4 waves x 64)
constexpr int BPK2 = Mm / RPB2;      // 512

__global__ __launch_bounds__(256) void scatter_mfma_kernel(
    const unsigned short* __restrict__ xb, const unsigned short* __restrict__ Wf,
    const int* __restrict__ in_idx, const int* __restrict__ out_idx,
    float* __restrict__ out)
{
    const int tid  = threadIdx.x;
    const int lane = tid & 63;
    const int w    = tid >> 6;
    const int k     = blockIdx.x / BPK2;
    const int chunk = blockIdx.x % BPK2;
    const int m0    = chunk * RPB2 + w * 64;

    const int lrow = lane & 15;
    const int lgrp = lane >> 4;

    // B fragments for W[k]: 4 col-tiles x 2 K-chunks, 8 bf16/lane each
    const unsigned short* Wk = Wf + (size_t)k * 4096;
    bf16x8 B[4][2];
#pragma unroll
    for (int ct = 0; ct < 4; ++ct)
#pragma unroll
        for (int kk = 0; kk < 2; ++kk)
            B[ct][kk] = *reinterpret_cast<const bf16x8*>(Wk + ((ct * 2 + kk) * 64 + lane) * 8);

    const int* inI  = in_idx  + (size_t)k * Mm + m0;
    const int* outI = out_idx + (size_t)k * Mm + m0;

#pragma unroll
    for (int rt = 0; rt < 4; ++rt) {   // 4 row-tiles of 16 rows
        const int base = rt * 16;
        const int ridx = inI[base + lrow];
        // A fragment: lane holds row (lane&15), k = (lane>>4)*8 + [0..7] (+32 for chunk 1)
        const unsigned short* xr = xb + (size_t)ridx * Cc + lgrp * 8;
        const bf16x8 A0 = *reinterpret_cast<const bf16x8*>(xr);
        const bf16x8 A1 = *reinterpret_cast<const bf16x8*>(xr + 32);

        int oi[4];
#pragma unroll
        for (int r = 0; r < 4; ++r) oi[r] = outI[base + lgrp * 4 + r];

        f32x4 acc[4];
#pragma unroll
        for (int ct = 0; ct < 4; ++ct) {
            acc[ct] = __builtin_amdgcn_mfma_f32_16x16x32_bf16(
                A0, B[ct][0], (f32x4){0.f, 0.f, 0.f, 0.f}, 0, 0, 0);
            acc[ct] = __builtin_amdgcn_mfma_f32_16x16x32_bf16(
                A1, B[ct][1], acc[ct], 0, 0, 0);
        }
        // C/D layout: col = lane&15, row = (lane>>4)*4 + r
#pragma unroll
        for (int ct = 0; ct < 4; ++ct)
#pragma unroll
            for (int r = 0; r < 4; ++r)
                atomicAdd(out + (size_t)oi[r] * Cc + ct * 16 + lrow, acc[ct][r]);
    }
}

// ---------------- fp32 fallback (round-1 path, used if ws too small) ----------------
constexpr int ROWS_PER_WAVE = 32;
constexpr int WAVES_PER_BLOCK = 4;
constexpr int ROWS_PER_BLOCK = ROWS_PER_WAVE * WAVES_PER_BLOCK;
constexpr int BLOCKS_PER_K = Mm / ROWS_PER_BLOCK;

__global__ __launch_bounds__(256) void scatter_gemm_kernel(
    const float* __restrict__ x, const float* __restrict__ W,
    const int* __restrict__ in_idx, const int* __restrict__ out_idx,
    float* __restrict__ out)
{
    const int tid  = threadIdx.x;
    const int lane = tid & 63;
    const int w    = tid >> 6;
    const int k     = blockIdx.x / BLOCKS_PER_K;
    const int chunk = blockIdx.x % BLOCKS_PER_K;
    const int m0    = chunk * ROWS_PER_BLOCK + w * ROWS_PER_WAVE;

    const float* Wk = W + k * (Cc * Cc);
    float wcol[Cc];
#pragma unroll
    for (int i = 0; i < Cc; ++i) wcol[i] = Wk[i * Cc + lane];

    const int* inI  = in_idx  + (size_t)k * Mm + m0;
    const int* outI = out_idx + (size_t)k * Mm + m0;

    __shared__ float xs[WAVES_PER_BLOCK][ROWS_PER_WAVE][Cc];

    for (int r = 0; r < ROWS_PER_WAVE; ++r)
        xs[w][r][lane] = x[(size_t)inI[r] * Cc + lane];

    for (int r = 0; r < ROWS_PER_WAVE; ++r) {
        const float* xr = &xs[w][r][0];
        float acc = 0.f;
#pragma unroll
        for (int i = 0; i < Cc; i += 4) {
            const float4 xv = *reinterpret_cast<const float4*>(xr + i);
            acc = fmaf(xv.x, wcol[i + 0], acc);
            acc = fmaf(xv.y, wcol[i + 1], acc);
            acc = fmaf(xv.z, wcol[i + 2], acc);
            acc = fmaf(xv.w, wcol[i + 3], acc);
        }
        atomicAdd(out + (size_t)outI[r] * Cc + lane, acc);
    }
}

// ---------------- BN ----------------
constexpr int STAT_BLOCKS = 1024;

__global__ __launch_bounds__(256) void bn_stats_kernel(
    const float* __restrict__ out, float* __restrict__ stats)
{
    const int tid = threadIdx.x;
    const int c = tid & 63;
    const int g = tid >> 6;
    float s = 0.f, sq = 0.f;
    for (int r = blockIdx.x * 4 + g; r < Nn; r += gridDim.x * 4) {
        const float v = out[(size_t)r * Cc + c];
        s += v;
        sq = fmaf(v, v, sq);
    }
    __shared__ float lsum[4][64];
    __shared__ float lsq[4][64];
    lsum[g][c] = s;
    lsq[g][c]  = sq;
    __syncthreads();
    if (tid < 64) {
        atomicAdd(stats + c,      lsum[0][c] + lsum[1][c] + lsum[2][c] + lsum[3][c]);
        atomicAdd(stats + 64 + c, lsq[0][c] + lsq[1][c] + lsq[2][c] + lsq[3][c]);
    }
}

__global__ void bn_finalize_kernel(const float* __restrict__ stats,
                                   const float* __restrict__ gamma,
                                   const float* __restrict__ beta,
                                   float* __restrict__ ss)
{
    const int c = threadIdx.x;
    const float inv_n = 1.f / (float)Nn;
    const float mean = stats[c] * inv_n;
    const float var  = stats[64 + c] * inv_n - mean * mean;
    const float scale = gamma[c] * rsqrtf(var + BN_EPS);
    ss[c]      = scale;
    ss[64 + c] = beta[c] - mean * scale;
}

__global__ __launch_bounds__(256) void bn_apply_kernel(
    float* __restrict__ out, const float* __restrict__ ss)
{
    const size_t total4 = (size_t)Nn * Cc / 4;
    const float4* ssc = reinterpret_cast<const float4*>(ss);
    float4* o4 = reinterpret_cast<float4*>(out);
    for (size_t i = (size_t)blockIdx.x * blockDim.x + threadIdx.x; i < total4;
         i += (size_t)gridDim.x * blockDim.x) {
        const int c4 = (int)(i & 15);
        const float4 sc = ssc[c4];
        const float4 sh = ssc[16 + c4];
        float4 v = o4[i];
        v.x = fmaxf(fmaf(v.x, sc.x, sh.x), 0.f);
        v.y = fmaxf(fmaf(v.y, sc.y, sh.y), 0.f);
        v.z = fmaxf(fmaf(v.z, sc.z, sh.z), 0.f);
        v.w = fmaxf(fmaf(v.w, sc.w, sh.w), 0.f);
        o4[i] = v;
    }
}

extern "C" void kernel_launch(void* const* d_in, const int* in_sizes, int n_in,
                              void* d_out, int out_size, void* d_ws, size_t ws_size,
                              hipStream_t stream) {
    const float* x      = (const float*)d_in[0];
    const float* W      = (const float*)d_in[1];
    const float* gamma  = (const float*)d_in[2];
    const float* beta   = (const float*)d_in[3];
    const int*   in_idx = (const int*)d_in[4];
    const int*   out_idx= (const int*)d_in[5];
    float* out   = (float*)d_out;
    char*  ws    = (char*)d_ws;
    float* stats = (float*)ws;
    float* ss    = stats + 128;

    hipMemsetAsync(d_out, 0, (size_t)Nn * Cc * sizeof(float), stream);
    hipMemsetAsync(d_ws, 0, 256 * sizeof(float), stream);

    if (ws_size >= WS_NEEDED) {
        unsigned short* Wf = (unsigned short*)(ws + WF_OFF);
        unsigned short* xb = (unsigned short*)(ws + XB_OFF);
        convert_x_kernel<<<4096, 256, 0, stream>>>(x, xb);
        convert_w_kernel<<<(Kk * 4096 + 255) / 256, 256, 0, stream>>>(W, Wf);
        scatter_mfma_kernel<<<Kk * BPK2, 256, 0, stream>>>(xb, Wf, in_idx, out_idx, out);
    } else {
        scatter_gemm_kernel<<<Kk * BLOCKS_PER_K, 256, 0, stream>>>(x, W, in_idx, out_idx, out);
    }

    bn_stats_kernel<<<STAT_BLOCKS, 256, 0, stream>>>(out, stats);
    bn_finalize_kernel<<<1, 64, 0, stream>>>(stats, gamma, beta, ss);
    bn_apply_kernel<<<4096, 256, 0, stream>>>(out, ss);
}